// Round 1
// baseline (1183.998 us; speedup 1.0000x reference)
//
#include <hip/hip_runtime.h>

typedef __attribute__((ext_vector_type(8))) short short8;
typedef __attribute__((ext_vector_type(4))) float f32x4;

#define NT   256
#define ROWS 32

// ---- workspace byte layout (prep output): bf16 hi/lo planes, k-major per col ----
// W1t: [2][272 cols][800 k]  (cols 0..255 = W1, 256..271 = Wp; k padded 784->800)
#define W1T_PL  435200
#define W1T_COL 1600
#define W2T_OFF 870400   // [2][256][256]
#define W2T_PL  131072
#define W2T_COL 512
#define WLT_OFF 1132544  // [2][784][16]
#define WLT_PL  25088
#define WLT_COL 32
// total ws bytes needed: 1182720

// ---- LDS byte layout (phase-aliased) ----
#define OFF_WCH 0        // 34816: W1 chunk | W2 chunk | Gs (stride 1040) | Wl image (50176)
#define OFF_XT  34816    // 4096: X chunk bf16 hi/lo
#define OFF_H   38912    // 32768: H fp32 [32][256] swizzled
#define OFF_YS  50176    // 2048: y bf16 hi/lo planes (H dead by then; beyond Wl image end)
#define OFF_XIP 71680    // 8192: xi partials [4][32][16] f32
#define LDS_SZ  79872    // 2 blocks/CU

#define MFMA16(a,b,c) __builtin_amdgcn_mfma_f32_16x16x32_bf16(a,b,c,0,0,0)

__device__ __forceinline__ unsigned short bf16_rn(float x){
  unsigned u = __float_as_uint(x);
  return (unsigned short)((u + 0x7fffu + ((u >> 16) & 1u)) >> 16);
}
__device__ __forceinline__ float bf16f(unsigned short h){
  return __uint_as_float(((unsigned)h) << 16);
}

__device__ __forceinline__ void glds16(const void* g, void* s){
#if __has_builtin(__builtin_amdgcn_global_load_lds)
  __builtin_amdgcn_global_load_lds((const __attribute__((address_space(1))) void*)g,
                                   (__attribute__((address_space(3))) void*)s, 16, 0, 0);
#else
  const int lane = (int)(threadIdx.x & 63u);
  *(short8*)((char*)s + lane*16) = *(const short8*)((const char*)g);
#endif
}

// ---------------- prep: split weights into bf16 hi/lo fragment layout ----------------
__global__ __launch_bounds__(256)
void prep_w(const float* __restrict__ W1, const float* __restrict__ W2,
            const float* __restrict__ Wp, const float* __restrict__ Wl,
            unsigned short* __restrict__ ws)
{
  const int u = blockIdx.x * 256 + threadIdx.x;
  float v[8];
  int bh, blo;
  if (u < 27200) {                       // 100 kg-groups x 272 cols (kg-major: coalesced reads)
    int kg = u / 272, col = u - kg*272;
    #pragma unroll
    for (int j = 0; j < 8; ++j) {
      int k = kg*8 + j;
      v[j] = (k < 784) ? ((col < 256) ? W1[k*256 + col] : Wp[k*16 + (col-256)]) : 0.0f;
    }
    bh = col*800 + kg*8; blo = bh + 217600;
  } else if (u < 35392) {                // W2: 32 kg x 256 cols
    int q = u - 27200;
    int kg = q >> 8, col = q & 255;
    #pragma unroll
    for (int j = 0; j < 8; ++j) v[j] = W2[(kg*8+j)*256 + col];
    bh = 435200 + col*256 + kg*8; blo = bh + 65536;
  } else if (u < 36960) {                // Wl: 2 kg x 784 cols
    int q = u - 35392;
    int kg = (q >= 784) ? 1 : 0; int col = q - kg*784;
    #pragma unroll
    for (int j = 0; j < 8; ++j) v[j] = Wl[(kg*8+j)*784 + col];
    bh = 566272 + col*16 + kg*8; blo = bh + 12544;
  } else return;
  short8 hv, lv;
  #pragma unroll
  for (int j = 0; j < 8; ++j) {
    unsigned short hh = bf16_rn(v[j]);
    hv[j] = (short)hh;
    lv[j] = (short)bf16_rn(v[j] - bf16f(hh));
  }
  *(short8*)&ws[bh]  = hv;
  *(short8*)&ws[blo] = lv;
}

// ---------------- main fused kernel ----------------
__global__ __launch_bounds__(NT, 2)
void riemann_mfma(const float* __restrict__ x, const float* __restrict__ tvec,
                  const float* __restrict__ b1g, const float* __restrict__ b2g,
                  const float* __restrict__ bpg, const float* __restrict__ blg,
                  const char* __restrict__ wst, float* __restrict__ out)
{
  __shared__ __align__(16) char lds[LDS_SZ];
  const int tid = threadIdx.x;
  const int wv  = tid >> 6;
  const int l   = tid & 63;
  const int lr  = l & 15;
  const int lg  = l >> 4;
  const int row0 = (int)blockIdx.x * ROWS;

  const f32x4 Z4 = {0.f, 0.f, 0.f, 0.f};
  const short8 Z8 = {0,0,0,0,0,0,0,0};

  f32x4 acc[2][4];
  f32x4 xia[2];
  #pragma unroll
  for (int mt = 0; mt < 2; ++mt) {
    xia[mt] = Z4;
    #pragma unroll
    for (int nt = 0; nt < 4; ++nt) acc[mt][nt] = Z4;
  }

  // ---------------- Phase 1: H = relu(X W1 + b1), xi = X Wp (MFMA bf16x3) ----------------
  const int xrow = tid >> 3;   // 0..31
  const int kq   = tid & 7;    // 4 floats each
  char* xwrh = lds + OFF_XT + xrow*64 + (((kq>>1) ^ ((xrow>>1)&3))<<4) + (kq&1)*8;

  for (int kc = 0; kc < 25; ++kc) {
    { // X chunk: load fp32, split hi/lo, swizzled LDS write
      const int kb = kc*32 + kq*4;
      f32x4 xv = Z4;
      if (kb < 784) xv = *(const f32x4*)(x + (long)(row0 + xrow)*784 + kb);
      unsigned long long hq = 0, lq = 0;
      #pragma unroll
      for (int e = 0; e < 4; ++e) {
        unsigned short hh = bf16_rn(xv[e]);
        unsigned short ll = bf16_rn(xv[e] - bf16f(hh));
        hq |= ((unsigned long long)hh) << (16*e);
        lq |= ((unsigned long long)ll) << (16*e);
      }
      *(unsigned long long*)xwrh = hq;
      *(unsigned long long*)(xwrh + 2048) = lq;
    }
    // W1|Wp chunk: 34 KiB via global_load_lds (source pre-swizzled, LDS linear)
    #pragma unroll
    for (int i2 = 0; i2 < 9; ++i2) {
      int i = wv + i2*4;
      if (i < 34) {
        int f = i*64 + l;
        int pl = (f >= 1088) ? 1 : 0;
        int r  = f - pl*1088;
        int col = r >> 2, kgp = r & 3;
        glds16(wst + pl*W1T_PL + col*W1T_COL + kc*64 + ((kgp ^ ((col>>1)&3)) << 4),
               lds + OFF_WCH + i*1024);
      }
    }
    __syncthreads();

    short8 af[2][2];
    #pragma unroll
    for (int mt = 0; mt < 2; ++mt) {
      int row = mt*16 + lr;
      int sl = lg ^ ((row>>1)&3);
      af[0][mt] = *(const short8*)(lds + OFF_XT +        row*64 + sl*16);
      af[1][mt] = *(const short8*)(lds + OFF_XT + 2048 + row*64 + sl*16);
    }
    short8 bfr[2][4];
    #pragma unroll
    for (int nt = 0; nt < 4; ++nt) {
      int col = wv*64 + nt*16 + lr;
      int sl = lg ^ ((col>>1)&3);
      bfr[0][nt] = *(const short8*)(lds + OFF_WCH +         col*64 + sl*16);
      bfr[1][nt] = *(const short8*)(lds + OFF_WCH + 17408 + col*64 + sl*16);
    }
    #pragma unroll
    for (int mt = 0; mt < 2; ++mt)
      #pragma unroll
      for (int nt = 0; nt < 4; ++nt) {
        acc[mt][nt] = MFMA16(af[0][mt], bfr[0][nt], acc[mt][nt]);
        acc[mt][nt] = MFMA16(af[0][mt], bfr[1][nt], acc[mt][nt]);
        acc[mt][nt] = MFMA16(af[1][mt], bfr[0][nt], acc[mt][nt]);
      }
    if ((kc & 3) == wv) {  // xi contribution, round-robined over waves
      int colx = 256 + lr;
      int slx = lg ^ ((colx>>1)&3);
      short8 bx0 = *(const short8*)(lds + OFF_WCH +         colx*64 + slx*16);
      short8 bx1 = *(const short8*)(lds + OFF_WCH + 17408 + colx*64 + slx*16);
      #pragma unroll
      for (int mt = 0; mt < 2; ++mt) {
        xia[mt] = MFMA16(af[0][mt], bx0, xia[mt]);
        xia[mt] = MFMA16(af[0][mt], bx1, xia[mt]);
        xia[mt] = MFMA16(af[1][mt], bx0, xia[mt]);
      }
    }
    __syncthreads();
  }

  // epilogue: H (bias+relu) -> LDS fp32 (kg-swizzled); xi partials -> LDS
  #pragma unroll
  for (int nt = 0; nt < 4; ++nt) {
    int col = wv*64 + nt*16 + lr;
    float b1v = b1g[col];
    int cb = (col >> 5)*128 + (col & 7)*4;
    int kgw = (col >> 3) & 3;
    #pragma unroll
    for (int mt = 0; mt < 2; ++mt)
      #pragma unroll
      for (int r = 0; r < 4; ++r) {
        int row = mt*16 + lg*4 + r;
        float v = acc[mt][nt][r] + b1v;
        v = v > 0.f ? v : 0.f;
        *(float*)(lds + OFF_H + row*1024 + cb + ((kgw ^ (row&3))<<5)) = v;
      }
  }
  #pragma unroll
  for (int mt = 0; mt < 2; ++mt)
    #pragma unroll
    for (int r = 0; r < 4; ++r) {
      int row = mt*16 + lg*4 + r;
      *(float*)(lds + OFF_XIP + wv*2048 + row*64 + lr*4) = xia[mt][r];
    }
  __syncthreads();

  // ---------------- Phase 2: g_flat = H W2 + b2 (MFMA bf16x3) ----------------
  f32x4 ac2[2][4];
  #pragma unroll
  for (int mt = 0; mt < 2; ++mt)
    #pragma unroll
    for (int nt = 0; nt < 4; ++nt) ac2[mt][nt] = Z4;

  for (int kc = 0; kc < 8; ++kc) {
    #pragma unroll
    for (int i2 = 0; i2 < 8; ++i2) {
      int i = wv + i2*4;
      int f = i*64 + l;
      int pl = f >> 10;
      int r  = f & 1023;
      int col = r >> 2, kgp = r & 3;
      glds16(wst + W2T_OFF + pl*W2T_PL + col*W2T_COL + kc*64 + ((kgp ^ ((col>>1)&3)) << 4),
             lds + OFF_WCH + i*1024);
    }
    __syncthreads();
    short8 ah[2], alo[2];
    #pragma unroll
    for (int mt = 0; mt < 2; ++mt) {
      int row = mt*16 + lr;
      const char* hb = lds + OFF_H + row*1024 + kc*128 + ((lg ^ (row&3))<<5);
      float hv[8];
      *(f32x4*)&hv[0] = *(const f32x4*)hb;
      *(f32x4*)&hv[4] = *(const f32x4*)(hb + 16);
      #pragma unroll
      for (int j = 0; j < 8; ++j) {
        unsigned short hh = bf16_rn(hv[j]);
        ah[mt][j]  = (short)hh;
        alo[mt][j] = (short)bf16_rn(hv[j] - bf16f(hh));
      }
    }
    short8 b2f[2][4];
    #pragma unroll
    for (int nt = 0; nt < 4; ++nt) {
      int col = wv*64 + nt*16 + lr;
      int sl = lg ^ ((col>>1)&3);
      b2f[0][nt] = *(const short8*)(lds + OFF_WCH +         col*64 + sl*16);
      b2f[1][nt] = *(const short8*)(lds + OFF_WCH + 16384 + col*64 + sl*16);
    }
    #pragma unroll
    for (int mt = 0; mt < 2; ++mt)
      #pragma unroll
      for (int nt = 0; nt < 4; ++nt) {
        ac2[mt][nt] = MFMA16(ah[mt],  b2f[0][nt], ac2[mt][nt]);
        ac2[mt][nt] = MFMA16(ah[mt],  b2f[1][nt], ac2[mt][nt]);
        ac2[mt][nt] = MFMA16(alo[mt], b2f[0][nt], ac2[mt][nt]);
      }
    __syncthreads();
  }
  // epilogue: A = g_flat + b2 -> Gs (stride 1040 B for bank spread)
  #pragma unroll
  for (int nt = 0; nt < 4; ++nt) {
    int col = wv*64 + nt*16 + lr;
    float b2v = b2g[col];
    #pragma unroll
    for (int mt = 0; mt < 2; ++mt)
      #pragma unroll
      for (int r = 0; r < 4; ++r) {
        int row = mt*16 + lg*4 + r;
        *(float*)(lds + OFF_WCH + row*1040 + col*4) = ac2[mt][nt][r] + b2v;
      }
  }
  __syncthreads();

  // ------- Phase 3+4: g = A A^T + 0.1 I and Gauss-Jordan, all in registers via shfl -------
  const int grp = tid >> 4;
  const int j16 = tid & 15;   // this lane owns matrix-row j16
  for (int it = 0; it < 2; ++it) {
    int m = it*16 + grp;
    float a[16];
    const char* gb = lds + OFF_WCH + m*1040 + j16*64;
    *(f32x4*)&a[0]  = *(const f32x4*)(gb);
    *(f32x4*)&a[4]  = *(const f32x4*)(gb + 16);
    *(f32x4*)&a[8]  = *(const f32x4*)(gb + 32);
    *(f32x4*)&a[12] = *(const f32x4*)(gb + 48);
    float xs = *(const float*)(lds + OFF_XIP +        m*64 + j16*4)
             + *(const float*)(lds + OFF_XIP + 2048 + m*64 + j16*4)
             + *(const float*)(lds + OFF_XIP + 4096 + m*64 + j16*4)
             + *(const float*)(lds + OFF_XIP + 6144 + m*64 + j16*4)
             + bpg[j16];
    float rhs = -xs / (tvec[row0 + m] + 1e-6f);
    float rw[16];
    #pragma unroll
    for (int i = 0; i < 16; ++i) {
      float d = (i == j16) ? 0.1f : 0.0f;
      #pragma unroll
      for (int k = 0; k < 16; ++k) d += a[k] * __shfl(a[k], i, 16);
      rw[i] = d;
    }
    float rdv = 0.f;
    #pragma unroll
    for (int k = 0; k < 16; ++k) {
      float piv = __shfl(rw[k], k, 16);
      float rp = 1.0f / piv;
      float f = rw[k] * rp;
      f = (j16 == k) ? 0.0f : f;
      if (j16 == k) rdv = rp;
      #pragma unroll
      for (int q = k+1; q < 16; ++q)
        rw[q] -= f * __shfl(rw[q], k, 16);
      rhs -= f * __shfl(rhs, k, 16);
    }
    float y = rhs * rdv;
    unsigned short yh = bf16_rn(y);
    unsigned short yl = bf16_rn(y - bf16f(yh));
    *(unsigned short*)(lds + OFF_YS +        m*32 + j16*2) = yh;
    *(unsigned short*)(lds + OFF_YS + 1024 + m*32 + j16*2) = yl;
  }
  __syncthreads();

  // ---------------- Phase 5: out = y Wl + bl (MFMA, K=16 zero-padded to 32) ----------------
  #pragma unroll
  for (int i2 = 0; i2 < 13; ++i2) {
    int i = wv + i2*4;
    if (i < 49) {
      int f = i*64 + l;
      int pl = (f >= 1568) ? 1 : 0;
      int r  = f - pl*1568;
      int col = r >> 1, kg = r & 1;
      glds16(wst + WLT_OFF + pl*WLT_PL + col*WLT_COL + kg*16,
             lds + OFF_WCH + i*1024);
    }
  }
  __syncthreads();

  short8 ya[2][2];
  #pragma unroll
  for (int p = 0; p < 2; ++p)
    #pragma unroll
    for (int mt = 0; mt < 2; ++mt) {
      short8 v = Z8;
      if (lg < 2) v = *(const short8*)(lds + OFF_YS + p*1024 + (mt*16 + lr)*32 + lg*16);
      ya[p][mt] = v;
    }

  for (int nt = wv; nt < 49; nt += 4) {
    short8 w0 = Z8, w1v = Z8;
    if (lg < 2) {
      int col = nt*16 + lr;
      w0  = *(const short8*)(lds + OFF_WCH +         col*32 + lg*16);
      w1v = *(const short8*)(lds + OFF_WCH + 25088 + col*32 + lg*16);
    }
    float blv = blg[nt*16 + lr];
    #pragma unroll
    for (int mt = 0; mt < 2; ++mt) {
      f32x4 a5 = Z4;
      a5 = MFMA16(ya[0][mt], w0,  a5);
      a5 = MFMA16(ya[0][mt], w1v, a5);
      a5 = MFMA16(ya[1][mt], w0,  a5);
      #pragma unroll
      for (int r = 0; r < 4; ++r)
        out[(long)(row0 + mt*16 + lg*4 + r)*784 + nt*16 + lr] = a5[r] + blv;
    }
  }
}

extern "C" void kernel_launch(void* const* d_in, const int* in_sizes, int n_in,
                              void* d_out, int out_size, void* d_ws, size_t ws_size,
                              hipStream_t stream)
{
  (void)n_in; (void)out_size; (void)ws_size;  // requires ws_size >= 1182720 bytes
  const float* x  = (const float*)d_in[0];
  const float* t  = (const float*)d_in[1];
  const float* W1 = (const float*)d_in[2];
  const float* b1 = (const float*)d_in[3];
  const float* W2 = (const float*)d_in[4];
  const float* b2 = (const float*)d_in[5];
  const float* Wp = (const float*)d_in[6];
  const float* bp = (const float*)d_in[7];
  const float* Wl = (const float*)d_in[8];
  const float* bl = (const float*)d_in[9];
  float* out = (float*)d_out;
  const int B = in_sizes[1];

  hipLaunchKernelGGL(prep_w, dim3(145), dim3(256), 0, stream,
                     W1, W2, Wp, Wl, (unsigned short*)d_ws);
  hipLaunchKernelGGL(riemann_mfma, dim3(B / ROWS), dim3(NT), 0, stream,
                     x, t, b1, b2, bp, bl, (const char*)d_ws, out);
}

// Round 2
// 1088.855 us; speedup vs baseline: 1.0874x; 1.0874x over previous
//
#include <hip/hip_runtime.h>

typedef __attribute__((ext_vector_type(8))) short short8;
typedef __attribute__((ext_vector_type(4))) float f32x4;

#define NT   256
#define ROWS 32

// ---- workspace byte layout (prep output): bf16 hi/lo planes, k-major per col ----
// W1t: [2][272 cols][800 k]  (cols 0..255 = W1, 256..271 = Wp; k padded 784->800)
#define W1T_PL  435200
#define W1T_COL 1600
#define W2T_OFF 870400   // [2][256][256]
#define W2T_PL  131072
#define W2T_COL 512
#define WLT_OFF 1132544  // [2][784][16]
#define WLT_PL  25088
#define WLT_COL 32
// total ws bytes needed: 1182720

// ---- LDS byte layout (phase-aliased), 79872 B -> 2 blocks/CU ----
#define OFF_W0   0        // 34816: W1 chunk slot0 | W2 chunk (32768) | A fp32 (32768) | Wl image start
#define OFF_W1   34816    // 34816: W1 chunk slot1 | H bf16 hi/lo (32768) in phase>=2
#define OFF_H    34816    // H_hi 16384 + H_lo 16384 (aliases slot1)
#define OFF_X0   69632    // 4096: X chunk buf0 (hi 2048 + lo 2048)
#define OFF_X1   73728    // 4096: X chunk buf1
#define OFF_XIP  69632    // 8192: xi partials [4 waves][32 rows][16] f32 (aliases dead X bufs)
#define OFF_YS   77824    // 2048: y bf16 hi/lo planes
#define LDS_SZ   79872

#define MFMA16(a,b,c) __builtin_amdgcn_mfma_f32_16x16x32_bf16(a,b,c,0,0,0)

__device__ __forceinline__ unsigned short bf16_rn(float x){
  unsigned u = __float_as_uint(x);
  return (unsigned short)((u + 0x7fffu + ((u >> 16) & 1u)) >> 16);
}
__device__ __forceinline__ float bf16f(unsigned short h){
  return __uint_as_float(((unsigned)h) << 16);
}

__device__ __forceinline__ void glds16(const void* g, void* s){
#if __has_builtin(__builtin_amdgcn_global_load_lds)
  __builtin_amdgcn_global_load_lds((const __attribute__((address_space(1))) void*)g,
                                   (__attribute__((address_space(3))) void*)s, 16, 0, 0);
#else
  const int lane = (int)(threadIdx.x & 63u);
  *(short8*)((char*)s + lane*16) = *(const short8*)((const char*)g);
#endif
}

// ---------------- prep: split weights into bf16 hi/lo fragment layout ----------------
__global__ __launch_bounds__(256)
void prep_w(const float* __restrict__ W1, const float* __restrict__ W2,
            const float* __restrict__ Wp, const float* __restrict__ Wl,
            unsigned short* __restrict__ ws)
{
  const int u = blockIdx.x * 256 + threadIdx.x;
  float v[8];
  int bh, blo;
  if (u < 27200) {                       // 100 kg-groups x 272 cols
    int kg = u / 272, col = u - kg*272;
    #pragma unroll
    for (int j = 0; j < 8; ++j) {
      int k = kg*8 + j;
      v[j] = (k < 784) ? ((col < 256) ? W1[k*256 + col] : Wp[k*16 + (col-256)]) : 0.0f;
    }
    bh = col*800 + kg*8; blo = bh + 217600;
  } else if (u < 35392) {                // W2: 32 kg x 256 cols
    int q = u - 27200;
    int kg = q >> 8, col = q & 255;
    #pragma unroll
    for (int j = 0; j < 8; ++j) v[j] = W2[(kg*8+j)*256 + col];
    bh = 435200 + col*256 + kg*8; blo = bh + 65536;
  } else if (u < 36960) {                // Wl: 2 kg x 784 cols
    int q = u - 35392;
    int kg = (q >= 784) ? 1 : 0; int col = q - kg*784;
    #pragma unroll
    for (int j = 0; j < 8; ++j) v[j] = Wl[(kg*8+j)*784 + col];
    bh = 566272 + col*16 + kg*8; blo = bh + 12544;
  } else return;
  short8 hv, lv;
  #pragma unroll
  for (int j = 0; j < 8; ++j) {
    unsigned short hh = bf16_rn(v[j]);
    hv[j] = (short)hh;
    lv[j] = (short)bf16_rn(v[j] - bf16f(hh));
  }
  *(short8*)&ws[bh]  = hv;
  *(short8*)&ws[blo] = lv;
}

// ---------------- main fused kernel ----------------
__global__ __launch_bounds__(NT, 2)
void riemann_mfma(const float* __restrict__ x, const float* __restrict__ tvec,
                  const float* __restrict__ b1g, const float* __restrict__ b2g,
                  const float* __restrict__ bpg, const float* __restrict__ blg,
                  const char* __restrict__ wst, float* __restrict__ out)
{
  __shared__ __align__(16) char lds[LDS_SZ];
  const int tid = threadIdx.x;
  const int wv  = tid >> 6;
  const int l   = tid & 63;
  const int lr  = l & 15;
  const int lg  = l >> 4;
  const int row0 = (int)blockIdx.x * ROWS;

  const f32x4 Z4 = {0.f, 0.f, 0.f, 0.f};
  const short8 Z8 = {0,0,0,0,0,0,0,0};

  f32x4 acc[2][4];
  f32x4 xia[2];
  #pragma unroll
  for (int mt = 0; mt < 2; ++mt) {
    xia[mt] = Z4;
    #pragma unroll
    for (int nt = 0; nt < 4; ++nt) acc[mt][nt] = Z4;
  }

  // ---------------- Phase 1: H = relu(X W1 + b1), xi = X Wp (MFMA bf16x3) ----------------
  const int xrow = tid >> 3;   // 0..31
  const int kq   = tid & 7;    // 4 floats each
  const int xwoff = xrow*64 + (((kq>>1) ^ ((xrow>>1)&3))<<4) + (kq&1)*8;

  auto loadX = [&](int ct)->f32x4 {
    f32x4 v = Z4;
    if (ct < 25) {
      int kb = ct*32 + kq*4;
      if (kb < 784) v = *(const f32x4*)(x + (long)(row0 + xrow)*784 + kb);
    }
    return v;
  };
  auto writeX = [&](const f32x4& xv, int slot){
    unsigned long long hq = 0, lq = 0;
    #pragma unroll
    for (int e = 0; e < 4; ++e) {
      unsigned short hh = bf16_rn(xv[e]);
      unsigned short ll = bf16_rn(xv[e] - bf16f(hh));
      hq |= ((unsigned long long)hh) << (16*e);
      lq |= ((unsigned long long)ll) << (16*e);
    }
    char* b = lds + (slot ? OFF_X1 : OFF_X0) + xwoff;
    *(unsigned long long*)b = hq;
    *(unsigned long long*)(b + 2048) = lq;
  };
  auto stageW1 = [&](int t, int slot){
    #pragma unroll
    for (int i2 = 0; i2 < 9; ++i2) {
      int i = wv + i2*4;
      if (i < 34) {
        int f = i*64 + l;
        int pl = (f >= 1088) ? 1 : 0;
        int r  = f - pl*1088;
        int col = r >> 2, kgp = r & 3;
        glds16(wst + pl*W1T_PL + col*W1T_COL + t*64 + ((kgp ^ ((col>>1)&3)) << 4),
               lds + (slot ? OFF_W1 : OFF_W0) + i*1024);
      }
    }
  };

  // prologue: chunk 0 staged, X0 written, X1 prefetched into regs
  f32x4 xv0 = loadX(0);
  stageW1(0, 0);
  writeX(xv0, 0);
  f32x4 xv = loadX(1);
  __syncthreads();

  for (int t = 0; t < 25; ++t) {
    const int cur = t & 1, nxt = cur ^ 1;
    if (t < 24) {
      stageW1(t + 1, nxt);     // issue next W chunk (overlaps compute below)
      writeX(xv, nxt);         // X chunk t+1 -> LDS (xv loaded an iter ago)
      xv = loadX(t + 2);       // prefetch X chunk t+2
    }
    const char* Xb = lds + (cur ? OFF_X1 : OFF_X0);
    const char* Wb = lds + (cur ? OFF_W1 : OFF_W0);

    short8 af[2][2];
    #pragma unroll
    for (int mt = 0; mt < 2; ++mt) {
      int row = mt*16 + lr;
      int sl = lg ^ ((row>>1)&3);
      af[0][mt] = *(const short8*)(Xb +        row*64 + sl*16);
      af[1][mt] = *(const short8*)(Xb + 2048 + row*64 + sl*16);
    }
    short8 bfr[2][4];
    #pragma unroll
    for (int nt = 0; nt < 4; ++nt) {
      int col = wv*64 + nt*16 + lr;
      int sl = lg ^ ((col>>1)&3);
      bfr[0][nt] = *(const short8*)(Wb +         col*64 + sl*16);
      bfr[1][nt] = *(const short8*)(Wb + 17408 + col*64 + sl*16);
    }
    #pragma unroll
    for (int mt = 0; mt < 2; ++mt)
      #pragma unroll
      for (int nt = 0; nt < 4; ++nt) {
        acc[mt][nt] = MFMA16(af[0][mt], bfr[0][nt], acc[mt][nt]);
        acc[mt][nt] = MFMA16(af[0][mt], bfr[1][nt], acc[mt][nt]);
        acc[mt][nt] = MFMA16(af[1][mt], bfr[0][nt], acc[mt][nt]);
      }
    if ((t & 3) == wv) {   // xi contribution, round-robined over waves
      int colx = 256 + lr;
      int slx = lg ^ ((colx>>1)&3);
      short8 bx0 = *(const short8*)(Wb +         colx*64 + slx*16);
      short8 bx1 = *(const short8*)(Wb + 17408 + colx*64 + slx*16);
      #pragma unroll
      for (int mt = 0; mt < 2; ++mt) {
        xia[mt] = MFMA16(af[0][mt], bx0, xia[mt]);
        xia[mt] = MFMA16(af[0][mt], bx1, xia[mt]);
        xia[mt] = MFMA16(af[1][mt], bx0, xia[mt]);
      }
    }
    __syncthreads();   // single barrier per chunk (drains stage + writes)
  }

  // epilogue: issue W2 chunk-0 stage first (overlaps conversion VALU)
  {
    #pragma unroll
    for (int i2 = 0; i2 < 8; ++i2) {
      int i = wv + i2*4;
      int f = i*64 + l;
      int pl = f >> 10, r = f & 1023;
      int col = r >> 2, kgp = r & 3;
      glds16(wst + W2T_OFF + pl*W2T_PL + col*W2T_COL + 0*64 + ((kgp ^ ((col>>1)&3)) << 4),
             lds + OFF_W0 + i*1024);
    }
  }
  // H (bias+relu) -> bf16 hi/lo planes, row-major [32][256], XOR-swizzled
  #pragma unroll
  for (int nt = 0; nt < 4; ++nt) {
    int col = wv*64 + nt*16 + lr;
    float b1v = b1g[col];
    #pragma unroll
    for (int mt = 0; mt < 2; ++mt)
      #pragma unroll
      for (int r = 0; r < 4; ++r) {
        int row = mt*16 + lg*4 + r;
        float v = acc[mt][nt][r] + b1v;
        v = v > 0.f ? v : 0.f;
        unsigned short hh = bf16_rn(v);
        unsigned short ll = bf16_rn(v - bf16f(hh));
        int bo = (row*512 + col*2) ^ ((row&7)<<4);
        *(unsigned short*)(lds + OFF_H +         bo) = hh;
        *(unsigned short*)(lds + OFF_H + 16384 + bo) = ll;
      }
  }
  // xi partials (aliases dead X dbuf)
  #pragma unroll
  for (int mt = 0; mt < 2; ++mt)
    #pragma unroll
    for (int r = 0; r < 4; ++r) {
      int row = mt*16 + lg*4 + r;
      *(float*)(lds + OFF_XIP + wv*2048 + row*64 + lr*4) = xia[mt][r];
    }
  __syncthreads();

  // ---------------- Phase 2: g_flat = H W2 + b2 (H pre-split bf16) ----------------
  f32x4 ac2[2][4];
  #pragma unroll
  for (int mt = 0; mt < 2; ++mt)
    #pragma unroll
    for (int nt = 0; nt < 4; ++nt) ac2[mt][nt] = Z4;

  for (int t = 0; t < 8; ++t) {
    short8 ah[2], alo[2];
    #pragma unroll
    for (int mt = 0; mt < 2; ++mt) {
      int row = mt*16 + lr;
      int bo = (row*512 + t*64 + lg*16) ^ ((row&7)<<4);
      ah[mt]  = *(const short8*)(lds + OFF_H +         bo);
      alo[mt] = *(const short8*)(lds + OFF_H + 16384 + bo);
    }
    short8 b2f[2][4];
    #pragma unroll
    for (int nt = 0; nt < 4; ++nt) {
      int col = wv*64 + nt*16 + lr;
      int sl = lg ^ ((col>>1)&3);
      b2f[0][nt] = *(const short8*)(lds + OFF_W0 +         col*64 + sl*16);
      b2f[1][nt] = *(const short8*)(lds + OFF_W0 + 16384 + col*64 + sl*16);
    }
    __syncthreads();           // all waves done reading W2 buffer
    if (t < 7) {               // stage next W2 chunk; overlaps MFMAs below
      #pragma unroll
      for (int i2 = 0; i2 < 8; ++i2) {
        int i = wv + i2*4;
        int f = i*64 + l;
        int pl = f >> 10, r = f & 1023;
        int col = r >> 2, kgp = r & 3;
        glds16(wst + W2T_OFF + pl*W2T_PL + col*W2T_COL + (t+1)*64 + ((kgp ^ ((col>>1)&3)) << 4),
               lds + OFF_W0 + i*1024);
      }
    }
    #pragma unroll
    for (int mt = 0; mt < 2; ++mt)
      #pragma unroll
      for (int nt = 0; nt < 4; ++nt) {
        ac2[mt][nt] = MFMA16(ah[mt],  b2f[0][nt], ac2[mt][nt]);
        ac2[mt][nt] = MFMA16(ah[mt],  b2f[1][nt], ac2[mt][nt]);
        ac2[mt][nt] = MFMA16(alo[mt], b2f[0][nt], ac2[mt][nt]);
      }
    __syncthreads();
  }
  // A = g_flat + b2 -> fp32 [32][256] at OFF_W0 (W2 chunks dead)
  #pragma unroll
  for (int nt = 0; nt < 4; ++nt) {
    int col = wv*64 + nt*16 + lr;
    float b2v = b2g[col];
    #pragma unroll
    for (int mt = 0; mt < 2; ++mt)
      #pragma unroll
      for (int r = 0; r < 4; ++r) {
        int row = mt*16 + lg*4 + r;
        *(float*)(lds + OFF_W0 + row*1024 + col*4) = ac2[mt][nt][r] + b2v;
      }
  }
  __syncthreads();

  // ------- Phase 3+4: g = A A^T + 0.1 I; Gauss-Jordan in registers via shfl -------
  const int grp = tid >> 4;
  const int j16 = tid & 15;    // lane owns matrix-row j16
  float aA[16], aB[16];
  {
    const char* g0 = lds + OFF_W0 + grp*1024 + j16*64;
    const char* g1 = lds + OFF_W0 + (16+grp)*1024 + j16*64;
    *(f32x4*)&aA[0]  = *(const f32x4*)(g0);
    *(f32x4*)&aA[4]  = *(const f32x4*)(g0 + 16);
    *(f32x4*)&aA[8]  = *(const f32x4*)(g0 + 32);
    *(f32x4*)&aA[12] = *(const f32x4*)(g0 + 48);
    *(f32x4*)&aB[0]  = *(const f32x4*)(g1);
    *(f32x4*)&aB[4]  = *(const f32x4*)(g1 + 16);
    *(f32x4*)&aB[8]  = *(const f32x4*)(g1 + 32);
    *(f32x4*)&aB[12] = *(const f32x4*)(g1 + 48);
  }
  float bpv = bpg[j16];
  float xs0 = *(const float*)(lds + OFF_XIP +        grp*64 + j16*4)
            + *(const float*)(lds + OFF_XIP + 2048 + grp*64 + j16*4)
            + *(const float*)(lds + OFF_XIP + 4096 + grp*64 + j16*4)
            + *(const float*)(lds + OFF_XIP + 6144 + grp*64 + j16*4) + bpv;
  float xs1 = *(const float*)(lds + OFF_XIP +        (16+grp)*64 + j16*4)
            + *(const float*)(lds + OFF_XIP + 2048 + (16+grp)*64 + j16*4)
            + *(const float*)(lds + OFF_XIP + 4096 + (16+grp)*64 + j16*4)
            + *(const float*)(lds + OFF_XIP + 6144 + (16+grp)*64 + j16*4) + bpv;
  float rhs0 = -xs0 / (tvec[row0 + grp] + 1e-6f);
  float rhs1 = -xs1 / (tvec[row0 + 16 + grp] + 1e-6f);
  __syncthreads();             // all A/xi reads complete

  // issue Wl staging now; hides under the solve below
  {
    #pragma unroll
    for (int i2 = 0; i2 < 13; ++i2) {
      int i = wv + i2*4;
      if (i < 49) {
        int f = i*64 + l;
        int pl = (f >= 1568) ? 1 : 0;
        int r  = f - pl*1568;
        int col = r >> 1, kg = r & 1;
        glds16(wst + WLT_OFF + pl*WLT_PL + col*WLT_COL + kg*16,
               lds + OFF_W0 + i*1024);
      }
    }
  }
  {
    float rw[16];
    #pragma unroll
    for (int i = 0; i < 16; ++i) {
      float d = (i == j16) ? 0.1f : 0.0f;
      #pragma unroll
      for (int k = 0; k < 16; ++k) d += aA[k] * __shfl(aA[k], i, 16);
      rw[i] = d;
    }
    float rdv = 0.f;
    #pragma unroll
    for (int k = 0; k < 16; ++k) {
      float piv = __shfl(rw[k], k, 16);
      float rp = 1.0f / piv;
      float f = rw[k] * rp;
      f = (j16 == k) ? 0.0f : f;
      if (j16 == k) rdv = rp;
      #pragma unroll
      for (int q = k+1; q < 16; ++q)
        rw[q] -= f * __shfl(rw[q], k, 16);
      rhs0 -= f * __shfl(rhs0, k, 16);
    }
    float y = rhs0 * rdv;
    unsigned short yh = bf16_rn(y);
    unsigned short yl = bf16_rn(y - bf16f(yh));
    *(unsigned short*)(lds + OFF_YS +        grp*32 + j16*2) = yh;
    *(unsigned short*)(lds + OFF_YS + 1024 + grp*32 + j16*2) = yl;
  }
  {
    float rw[16];
    #pragma unroll
    for (int i = 0; i < 16; ++i) {
      float d = (i == j16) ? 0.1f : 0.0f;
      #pragma unroll
      for (int k = 0; k < 16; ++k) d += aB[k] * __shfl(aB[k], i, 16);
      rw[i] = d;
    }
    float rdv = 0.f;
    #pragma unroll
    for (int k = 0; k < 16; ++k) {
      float piv = __shfl(rw[k], k, 16);
      float rp = 1.0f / piv;
      float f = rw[k] * rp;
      f = (j16 == k) ? 0.0f : f;
      if (j16 == k) rdv = rp;
      #pragma unroll
      for (int q = k+1; q < 16; ++q)
        rw[q] -= f * __shfl(rw[q], k, 16);
      rhs1 -= f * __shfl(rhs1, k, 16);
    }
    float y = rhs1 * rdv;
    unsigned short yh = bf16_rn(y);
    unsigned short yl = bf16_rn(y - bf16f(yh));
    *(unsigned short*)(lds + OFF_YS +        (16+grp)*32 + j16*2) = yh;
    *(unsigned short*)(lds + OFF_YS + 1024 + (16+grp)*32 + j16*2) = yl;
  }
  __syncthreads();             // drains Wl stage + ys writes

  // ---------------- Phase 5: out = y Wl + bl (MFMA, K=16 zero-padded to 32) ----------------
  short8 ya[2][2];
  #pragma unroll
  for (int p = 0; p < 2; ++p)
    #pragma unroll
    for (int mt = 0; mt < 2; ++mt) {
      short8 v = Z8;
      if (lg < 2) v = *(const short8*)(lds + OFF_YS + p*1024 + (mt*16 + lr)*32 + lg*16);
      ya[p][mt] = v;
    }

  for (int nt = wv; nt < 49; nt += 4) {
    short8 w0 = Z8, w1v = Z8;
    if (lg < 2) {
      int col = nt*16 + lr;
      w0  = *(const short8*)(lds + OFF_W0 +         col*32 + lg*16);
      w1v = *(const short8*)(lds + OFF_W0 + 25088 + col*32 + lg*16);
    }
    float blv = blg[nt*16 + lr];
    #pragma unroll
    for (int mt = 0; mt < 2; ++mt) {
      f32x4 a5 = Z4;
      a5 = MFMA16(ya[0][mt], w0,  a5);
      a5 = MFMA16(ya[0][mt], w1v, a5);
      a5 = MFMA16(ya[1][mt], w0,  a5);
      #pragma unroll
      for (int r = 0; r < 4; ++r)
        out[(long)(row0 + mt*16 + lg*4 + r)*784 + nt*16 + lr] = a5[r] + blv;
    }
  }
}

extern "C" void kernel_launch(void* const* d_in, const int* in_sizes, int n_in,
                              void* d_out, int out_size, void* d_ws, size_t ws_size,
                              hipStream_t stream)
{
  (void)n_in; (void)out_size; (void)ws_size;  // requires ws_size >= 1182720 bytes
  const float* x  = (const float*)d_in[0];
  const float* t  = (const float*)d_in[1];
  const float* W1 = (const float*)d_in[2];
  const float* b1 = (const float*)d_in[3];
  const float* W2 = (const float*)d_in[4];
  const float* b2 = (const float*)d_in[5];
  const float* Wp = (const float*)d_in[6];
  const float* bp = (const float*)d_in[7];
  const float* Wl = (const float*)d_in[8];
  const float* bl = (const float*)d_in[9];
  float* out = (float*)d_out;
  const int B = in_sizes[1];

  hipLaunchKernelGGL(prep_w, dim3(145), dim3(256), 0, stream,
                     W1, W2, Wp, Wl, (unsigned short*)d_ws);
  hipLaunchKernelGGL(riemann_mfma, dim3(B / ROWS), dim3(NT), 0, stream,
                     x, t, b1, b2, bp, bl, (const char*)d_ws, out);
}